// Round 9
// baseline (384.944 us; speedup 1.0000x reference)
//
#include <hip/hip_runtime.h>

typedef unsigned short u16;
typedef __bf16 bf16x8 __attribute__((ext_vector_type(8)));
typedef float f32x4 __attribute__((ext_vector_type(4)));
typedef int i32x4 __attribute__((ext_vector_type(4)));
typedef int i32x2 __attribute__((ext_vector_type(2)));
// may_alias: LDS/global buffers are accessed as u16, i32x2/4, f32x4 and bf16x8 —
// without this, TBAA lets the compiler reorder the P-matrix stores vs loads.
typedef i32x4 i32x4_a __attribute__((may_alias));
typedef i32x2 i32x2_a __attribute__((may_alias));
typedef bf16x8 bf16x8_a __attribute__((may_alias));
typedef f32x4 f32x4_a __attribute__((may_alias));
typedef unsigned long long u64_a __attribute__((may_alias));

#define LOG2E 1.4426950408889634f

__device__ __forceinline__ float bf2f(u16 u) {
  union { unsigned int i; float f; } c;
  c.i = ((unsigned int)u) << 16;
  return c.f;
}
// Native cast -> v_cvt_pk_bf16_f32 (RNE).
__device__ __forceinline__ u16 f2bf(float f) {
  union { __bf16 h; u16 u; } c;
  c.h = (__bf16)f;
  return c.u;
}
// dual-dtype scalar load: isbf ? bf16[i] : f32[i]
__device__ __forceinline__ float gld(const void* p, int i, int isbf) {
  return isbf ? bf2f(((const u16*)p)[i]) : ((const float*)p)[i];
}
// XOR-swizzled LDS element offset (16B blocks swizzled by row low 3 bits).
__device__ __forceinline__ int sw(int row, int col, int rs) {
  return row * rs + ((((col >> 3) ^ (row & 7)) << 3) | (col & 7));
}
__device__ __forceinline__ f32x4 splat4(float x) {
  f32x4 v = {x, x, x, x};
  return v;
}

// ws layout (bytes):  [fragment-order operand layouts]
//   0      : wqkvF  bf16 [24ntg][4ks][64lane][8]  (98304)   ntg = outcol/16
//   98304  : pwF    bf16 [4sub][2nt][4ks][64lane][8]  (32768)
//   131072 : qkvb   f32  [384]        (1536)
//   132608 : bias16F f32 [4h][2mg][2qt][4kt][64lane][4r] (65536) — ×LOG2E
//   198144 : scalef f32  [4]          (16)     == exp(min(logit_scale, ln100))
//   198160 : pbf    f32  [128]        (512)
//   198672 : flag   u32  (1=bf16 inputs, 0=f32 inputs)
//   200704 : maskF  f32  [256w][2mg][2qt][4kt][64lane][4r]  (4MB, ×LOG2E,
//            OPTIONAL — only if ws_size permits)
#define WQKVT_OFF 0
#define PWT_OFF   98304
#define QKVB_OFF  131072
#define BIAS_OFF  132608
#define SCALE_OFF 198144
#define PB_OFF    198160
#define FLAG_OFF  198672
#define MASKF_OFF 200704
#define MASKF_NEED (200704ull + 4ull * 1024 * 1024)

// ---------------- dtype probe ----------------
__global__ void swin_detect(const unsigned int* __restrict__ xw,
                            unsigned int* __restrict__ flag) {
  int t = threadIdx.x;  // 64 threads
  int cnt = 0;
  for (int i = 0; i < 8; i++) {
    unsigned int w = xw[t * 8 + i];
    unsigned int lo = w & 0xffffu;
    unsigned int e = (lo >> 7) & 0xffu;
    if ((e >= 0x70u && e <= 0x82u) || lo == 0u) cnt++;
  }
  cnt += __shfl_xor(cnt, 1);
  cnt += __shfl_xor(cnt, 2);
  cnt += __shfl_xor(cnt, 4);
  cnt += __shfl_xor(cnt, 8);
  cnt += __shfl_xor(cnt, 16);
  cnt += __shfl_xor(cnt, 32);
  if (t == 0) *flag = (cnt >= 256) ? 1u : 0u;
}

// ---------------- setup: fragment-order weight layouts ----------------
__global__ void swin_setup(const void* __restrict__ qkv_w, const void* __restrict__ q_bias,
                           const void* __restrict__ v_bias, const void* __restrict__ ls,
                           const void* __restrict__ cpb_w1, const void* __restrict__ cpb_b1,
                           const void* __restrict__ cpb_w2, const void* __restrict__ proj_w,
                           const void* __restrict__ proj_b, char* __restrict__ ws) {
  const int b = blockIdx.x, t = threadIdx.x;
  const int isbf = (int)*(const unsigned int*)(ws + FLAG_OFF);
  u16* wqkvF = (u16*)(ws + WQKVT_OFF);
  u16* pwF = (u16*)(ws + PWT_OFF);
  float* qkvb = (float*)(ws + QKVB_OFF);
  float* bias16F = (float*)(ws + BIAS_OFF);
  float* scalef = (float*)(ws + SCALE_OFF);
  float* pbf = (float*)(ws + PB_OFF);

  if (b < 128) {
    // qkv_w row b (input-dim b): out-col c -> fragment addr; ntg = c/16.
    int ks = b >> 5, lq = (b >> 3) & 3, j = b & 7;
    for (int c = t; c < 384; c += 256) {
      int ntg = c >> 4, l16 = c & 15;
      int addr = ((ntg * 4 + ks) << 9) + ((lq * 16 + l16) << 3) + j;
      wqkvF[addr] = f2bf(gld(qkv_w, b * 384 + c, isbf));
    }
  } else if (b < 256) {    // proj_w row r=b-128 (input-dim)
    int r = b - 128;
    int ks = r >> 5, lq = (r >> 3) & 3, j = r & 7;
    if (t < 128) {
      int sub = t >> 5, rr = t & 31;
      int nt = rr >> 4, l16 = rr & 15;
      int addr = (((sub * 2 + nt) * 4 + ks) << 9) + ((lq * 16 + l16) << 3) + j;
      pwF[addr] = f2bf(gld(proj_w, r * 128 + t, isbf));
    }
  } else if (b == 256) {   // small vectors
    for (int o = t; o < 384; o += 256) {
      float v = 0.f;
      if (o < 128) v = gld(q_bias, o, isbf);
      else if (o >= 256) v = gld(v_bias, o - 256, isbf);
      qkvb[o] = v;
    }
    if (t < 128) pbf[t] = gld(proj_b, t, isbf);
    if (t < 4) scalef[t] = expf(fminf(gld(ls, t, isbf), 4.60517019f));
  } else {                 // CPB MLP -> 16*sigmoid*LOG2E, fragment-order
    __shared__ float w1[1024];   // [2][512]
    __shared__ float b1[512];
    __shared__ float w2[2048];   // [512][4]
    __shared__ float tab[225][4];
    for (int i = t; i < 1024; i += 256) w1[i] = gld(cpb_w1, i, isbf);
    for (int i = t; i < 512; i += 256) b1[i] = gld(cpb_b1, i, isbf);
    for (int i = t; i < 2048; i += 256) w2[i] = gld(cpb_w2, i, isbf);
    __syncthreads();
    if (t < 225) {
      int i = t / 15, j = t % 15;
      float c0, c1;
      {
        float tt = ((float)(i - 7) / 7.0f) * 8.0f;
        float s = (tt > 0.f) ? 1.f : ((tt < 0.f) ? -1.f : 0.f);
        c0 = s * log2f(fabsf(tt) + 1.f) / 3.0f;
      }
      {
        float tt = ((float)(j - 7) / 7.0f) * 8.0f;
        float s = (tt > 0.f) ? 1.f : ((tt < 0.f) ? -1.f : 0.f);
        c1 = s * log2f(fabsf(tt) + 1.f) / 3.0f;
      }
      float acc[4] = {0.f, 0.f, 0.f, 0.f};
      for (int jj = 0; jj < 512; jj++) {
        float h = fmaxf(c0 * w1[jj] + c1 * w1[512 + jj] + b1[jj], 0.f);
        #pragma unroll
        for (int hh = 0; hh < 4; hh++) acc[hh] += h * w2[jj * 4 + hh];
      }
      #pragma unroll
      for (int hh = 0; hh < 4; hh++) tab[t][hh] = acc[hh];
    }
    __syncthreads();
    // bias16F[e]: e = h*4096 + mg*2048 + qt*1024 + kt*256 + lane*4 + r
    //   q = 32mg+16qt+(lane&15), k = 16kt+4(lane>>4)+r; value ×LOG2E (exp2 path)
    for (int e = t; e < 4 * 64 * 64; e += 256) {
      int h = e >> 12, mg = (e >> 11) & 1, qt = (e >> 10) & 1;
      int kt = (e >> 8) & 3, lane = (e >> 2) & 63, r = e & 3;
      int q = 32 * mg + 16 * qt + (lane & 15);
      int kk = 16 * kt + 4 * (lane >> 4) + r;
      int dr = (q >> 3) - (kk >> 3) + 7;
      int dc = (q & 7) - (kk & 7) + 7;
      float v = tab[dr * 15 + dc][h];
      bias16F[e] = LOG2E * (16.f / (1.f + expf(-v)));
    }
  }
}

// ---------------- setup: fragment-order mask (optional, ×LOG2E) ----------
__global__ void swin_setup_mask(const void* __restrict__ mask, char* __restrict__ ws) {
  const int w = blockIdx.x, t = threadIdx.x;
  const int isbf = (int)*(const unsigned int*)(ws + FLAG_OFF);
  float* maskF = (float*)(ws + MASKF_OFF);
  #pragma unroll
  for (int i = 0; i < 16; i++) {
    int e = t + i * 256;               // 4096 elems per window
    int q = e >> 6, k = e & 63;
    int mg = q >> 5, qt = (q >> 4) & 1, l16 = q & 15;
    int kt = k >> 4, lq = (k >> 2) & 3, r = k & 3;
    int addr = w * 4096 + ((mg * 2 + qt) * 4 + kt) * 256 + ((lq * 16 + l16) << 2) + r;
    maskF[addr] = LOG2E * gld(mask, w * 4096 + e, isbf);
  }
}

// ---------------- fused per-window kernel (round-10) ----------------
// One block per window (B*256 blocks), 512 threads = 8 waves.
// Round-10 vs round-9 (165.5us, VALU 53%, occupancy 41% = 2 blocks/CU):
//   Occupancy wall = TOTAL regs ~112 (64 arch + 48 AGPR for acc1[2][6]).
//   Restructure so demand fits the 85-reg budget of 6 waves/SIMD:
//   1. HEAD-ALIGNED chunk-sequential GEMM1: wave (mg,h) computes k_h, v_h,
//      then q_h as three 32-col chunk-GEMMs -> acc peak 16 AGPR (was 48).
//      asm clobbers between chunks block X-fragment CSE (round-3 lesson).
//      Q (last chunk) held as 8 packed u32 across ONE barrier, written into
//      the dead X region.
//   2. LDS 48KB: X/Q [0,8K), K [8K,16K), VT [16K,24K); P overlays [0,16K)
//      (X+Q+K dead); AO overlays VT [16K,24K). 48KB*3 = 144 <= 160.
//   3. __launch_bounds__(512,6): demand ~80 fits -> no spill (rounds 3/5
//      failed because demand was ~112 >> 85; watch WRITE_SIZE == 131072).
//   4. exp2 softmax: LOG2E folded into q-prescale/bias16F/maskF at setup.
//   5. rsqrtf for q/k norms (was sqrt+div).
// Barriers: B0 (X), B1a (X reads done), B1b (Q/K/VT visible), B2 (pre-P),
//           B3 (pre-AO over VT), B4 (AO visible) = 6.
#define XQ_OFF 0
#define K_OFF 8192
#define VT_OFF 16384
#define P_OFF 0
#define AO_OFF 16384

template <int MF>
__global__ __launch_bounds__(512, 6) void swin_main(
    const void* __restrict__ x, const void* __restrict__ mask,
    const char* __restrict__ ws, void* __restrict__ out) {
  __shared__ __align__(16) u16 lds[24576];
  const f32x4 fz = {0.f, 0.f, 0.f, 0.f};

  const u16* wqkvF = (const u16*)(ws + WQKVT_OFF);
  const u16* pwF = (const u16*)(ws + PWT_OFF);
  const float* qkvb = (const float*)(ws + QKVB_OFF);
  const float* bias16F = (const float*)(ws + BIAS_OFF);
  const float* scalef = (const float*)(ws + SCALE_OFF);
  const float* pbf = (const float*)(ws + PB_OFF);
  const int isbf = (int)*(const unsigned int*)(ws + FLAG_OFF);

  const int tid = threadIdx.x;
  const int wid = tid >> 6;
  const int lane = tid & 63;
  const int ln16 = lane & 15;
  const int lq = lane >> 4;
  const int q8 = lq << 3;
  const int mg = wid >> 2;   // row half: 0/1
  const int sub = wid & 3;   // head (chunk mapping is head-aligned)

  const int wi = blockIdx.x;
  const int b = wi >> 8;
  const int rem = wi & 255;
  const int wy = rem >> 4, wx = rem & 15;
  const int xbase = ((b * 128 + wy * 8) * 128 + wx * 8) * 128;

  // ---- stage 1: X tile -> LDS as bf16 (coalesced) ----
  if (isbf) {
    const u16* xb = (const u16*)x;
    #pragma unroll
    for (int rep = 0; rep < 2; rep++) {
      int ch = tid + rep * 512;          // 1024 chunks of 8 elements
      int token = ch >> 4, dch = ch & 15;
      int r = token >> 3, c = token & 7;
      i32x4 v = *(const i32x4_a*)(xb + xbase + r * 16384 + c * 128 + dch * 8);
      *(i32x4_a*)(lds + XQ_OFF + sw(token, dch * 8, 128)) = v;
    }
  } else {
    const float* xf = (const float*)x;
    #pragma unroll
    for (int rep = 0; rep < 2; rep++) {
      int ch = tid + rep * 512;
      int token = ch >> 4, dch = ch & 15;
      int r = token >> 3, c = token & 7;
      const float* src = xf + xbase + r * 16384 + c * 128 + dch * 8;
      union { i32x4 v2[2]; float f[8]; } in;
      in.v2[0] = *(const i32x4_a*)(src);
      in.v2[1] = *(const i32x4_a*)(src + 4);
      union { u16 u[8]; i32x4 v; } o;
      #pragma unroll
      for (int d = 0; d < 8; d++) o.u[d] = f2bf(in.f[d]);
      *(i32x4_a*)(lds + XQ_OFF + sw(token, dch * 8, 128)) = o.v;
    }
  }
  __syncthreads();  // B0: X visible

  // ---- stage 2: GEMM1 as 3 sequential 32-col chunk-GEMMs (k, v, q) ----
  const float sc_q = scalef[sub] * LOG2E;  // logit scale × log2e folded into q
  f32x4 acc[2][2];
  unsigned int hq[8];

  // -- K chunk (cols 128 + 32*sub) --
  {
    const int n0 = 128 + 32 * sub;
    const int ntg = n0 >> 4;
    acc[0][0] = splat4(qkvb[n0 + ln16]);
    acc[0][1] = splat4(qkvb[n0 + 16 + ln16]);
    acc[1][0] = acc[0][0];
    acc[1][1] = acc[0][1];
    #pragma unroll
    for (int ks = 0; ks < 4; ks++) {
      bf16x8 a0 = *(const bf16x8_a*)(lds + XQ_OFF + sw(32 * mg + ln16, 32 * ks + q8, 128));
      bf16x8 a1 = *(const bf16x8_a*)(lds + XQ_OFF + sw(32 * mg + 16 + ln16, 32 * ks + q8, 128));
      bf16x8 b0 = *(const bf16x8_a*)(wqkvF + ((ntg * 4 + ks) << 9) + lane * 8);
      bf16x8 b1 = *(const bf16x8_a*)(wqkvF + (((ntg + 1) * 4 + ks) << 9) + lane * 8);
      acc[0][0] = __builtin_amdgcn_mfma_f32_16x16x32_bf16(a0, b0, acc[0][0], 0, 0, 0);
      acc[0][1] = __builtin_amdgcn_mfma_f32_16x16x32_bf16(a0, b1, acc[0][1], 0, 0, 0);
      acc[1][0] = __builtin_amdgcn_mfma_f32_16x16x32_bf16(a1, b0, acc[1][0], 0, 0, 0);
      acc[1][1] = __builtin_amdgcn_mfma_f32_16x16x32_bf16(a1, b1, acc[1][1], 0, 0, 0);
    }
    #pragma unroll
    for (int mt = 0; mt < 2; mt++)
      #pragma unroll
      for (int r = 0; r < 4; r++) {
        float x0 = acc[mt][0][r], x1 = acc[mt][1][r];
        float ss = x0 * x0 + x1 * x1;
        ss += __shfl_xor(ss, 1);
        ss += __shfl_xor(ss, 2);
        ss += __shfl_xor(ss, 4);
        ss += __shfl_xor(ss, 8);
        float inv = rsqrtf(fmaxf(ss, 1e-24f));
        int row = 32 * mg + 16 * mt + 4 * lq + r;
        lds[K_OFF + sw(row, sub * 32 + ln16, 128)] = f2bf(x0 * inv);
        lds[K_OFF + sw(row, sub * 32 + 16 + ln16, 128)] = f2bf(x1 * inv);
      }
  }
  asm volatile("" ::: "memory");  // block X-fragment CSE across chunks

  // -- V chunk (cols 256 + 32*sub): transposed, packed stores --
  {
    const int n0 = 256 + 32 * sub;
    const int ntg = n0 >> 4;
    acc[0][0] = splat4(qkvb[n0 + ln16]);
    acc[0][1] = splat4(qkvb[n0 + 16 + ln16]);
    acc[1][0] = acc[0][0];
    acc[1][1] = acc[0][1];
    #pragma unroll
    for (int ks = 0; ks < 4; ks++) {
      bf16x8 a0 = *(const bf16x8_a*)(lds + XQ_OFF + sw(32 * mg + ln16, 32 * ks + q8, 128));
      bf16x8 a1 = *(const bf16x8_a*)(lds + XQ_OFF + sw(32 * mg + 16 + ln16, 32 * ks + q8, 128));
      bf16x8 b0 = *(const bf16x8_a*)(wqkvF + ((ntg * 4 + ks) << 9) + lane * 8);
      bf16x8 b1 = *(const bf16x8_a*)(wqkvF + (((ntg + 1) * 4 + ks) << 9) + lane * 8);
      acc[0][0] = __builtin_amdgcn_mfma_f32_16x16x32_bf16(a0, b0, acc[0][0], 0, 0, 0);
      acc[0][1] = __builtin_amdgcn_mfma_f32_16x16x32_bf16(a0, b1, acc[0][1], 0, 0, 0);
      acc[1][0] = __builtin_amdgcn_mfma_f32_16x16x32_bf16(a1, b0, acc[1][0], 0, 0, 0);
      acc[1][1] = __builtin_amdgcn_mfma_f32_16x16x32_bf16(a1, b1, acc[1][1], 0, 0, 0);
    }
    #pragma unroll
    for (int mt = 0; mt < 2; mt++) {
      int c0 = 32 * mg + 16 * mt + 4 * lq;
      unsigned int w0 = (unsigned int)f2bf(acc[mt][0][0]) | ((unsigned int)f2bf(acc[mt][0][1]) << 16);
      unsigned int w1 = (unsigned int)f2bf(acc[mt][0][2]) | ((unsigned int)f2bf(acc[mt][0][3]) << 16);
      i32x2 wv = {(int)w0, (int)w1};
      *(i32x2_a*)(lds + VT_OFF + sw(sub * 32 + ln16, c0, 64)) = wv;
      unsigned int u0 = (unsigned int)f2bf(acc[mt][1][0]) | ((unsigned int)f2bf(acc[mt][1][1]) << 16);
      unsigned int u1 = (unsigned int)f2bf(acc[mt][1][2]) | ((unsigned int)f2bf(acc[mt][1][3]) << 16);
      i32x2 uv = {(int)u0, (int)u1};
      *(i32x2_a*)(lds + VT_OFF + sw(sub * 32 + 16 + ln16, c0, 64)) = uv;
    }
  }
  asm volatile("" ::: "memory");

  // -- Q chunk LAST (cols 32*sub): held in 8 packed regs, written post-B1a --
  {
    const int n0 = 32 * sub;
    const int ntg = n0 >> 4;
    acc[0][0] = splat4(qkvb[n0 + ln16]);
    acc[0][1] = splat4(qkvb[n0 + 16 + ln16]);
    acc[1][0] = acc[0][0];
    acc[1][1] = acc[0][1];
    #pragma unroll
    for (int ks = 0; ks < 4; ks++) {
      bf16x8 a0 = *(const bf16x8_a*)(lds + XQ_OFF + sw(32 * mg + ln16, 32 * ks + q8, 128));
      bf16x8 a1 = *(const bf16x8_a*)(lds + XQ_OFF + sw(32 * mg + 16 + ln16, 32 * ks + q8, 128));
      bf16x8 b0 = *(const bf16x8_a*)(wqkvF + ((ntg * 4 + ks) << 9) + lane * 8);
      bf16x8 b1 = *(const bf16x8_a*)(wqkvF + (((ntg + 1) * 4 + ks) << 9) + lane * 8);
      acc[0][0] = __builtin_amdgcn_mfma_f32_16x16x32_bf16(a0, b0, acc[0][0], 0, 0, 0);
      acc[0][1] = __builtin_amdgcn_mfma_f32_16x16x32_bf16(a0, b1, acc[0][1], 0, 0, 0);
      acc[1][0] = __builtin_amdgcn_mfma_f32_16x16x32_bf16(a1, b0, acc[1][0], 0, 0, 0);
      acc[1][1] = __builtin_amdgcn_mfma_f32_16x16x32_bf16(a1, b1, acc[1][1], 0, 0, 0);
    }
    #pragma unroll
    for (int mt = 0; mt < 2; mt++)
      #pragma unroll
      for (int r = 0; r < 4; r++) {
        float x0 = acc[mt][0][r], x1 = acc[mt][1][r];
        float ss = x0 * x0 + x1 * x1;
        ss += __shfl_xor(ss, 1);
        ss += __shfl_xor(ss, 2);
        ss += __shfl_xor(ss, 4);
        ss += __shfl_xor(ss, 8);
        float inv = sc_q * rsqrtf(fmaxf(ss, 1e-24f));
        hq[mt * 4 + r] = (unsigned int)f2bf(x0 * inv) | ((unsigned int)f2bf(x1 * inv) << 16);
      }
  }
  __syncthreads();  // B1a: all X reads done; K/VT writes issued

  // write held q into XQ region (overlays dead X)
  #pragma unroll
  for (int mt = 0; mt < 2; mt++)
    #pragma unroll
    for (int r = 0; r < 4; r++) {
      unsigned int pv = hq[mt * 4 + r];
      int row = 32 * mg + 16 * mt + 4 * lq + r;
      lds[XQ_OFF + sw(row, sub * 32 + ln16, 128)] = (u16)(pv & 0xffffu);
      lds[XQ_OFF + sw(row, sub * 32 + 16 + ln16, 128)] = (u16)(pv >> 16);
    }
  __syncthreads();  // B1b: Q/K/VT visible

  // ---- stage 3: S^T = k.(q·scale·log2e)^T + (bias+mask)·log2e (MFMA C) ----
  const int h = sub;
  f32x4 ST[4][2];
  if (MF) {
    const float* mrow = (const float*)(ws + MASKF_OFF) + rem * 4096;
    #pragma unroll
    for (int qt = 0; qt < 2; qt++)
      #pragma unroll
      for (int kt = 0; kt < 4; kt++) {
        int fo = mg * 2048 + qt * 1024 + kt * 256 + lane * 4;
        f32x4 bv = *(const f32x4_a*)(bias16F + h * 4096 + fo);
        f32x4 mv = *(const f32x4_a*)(mrow + fo);
        ST[kt][qt] = bv + mv;
      }
  } else {
    const u16* mk16 = (const u16*)mask;
    const float* mkf = (const float*)mask;
    #pragma unroll
    for (int qt = 0; qt < 2; qt++) {
      int q = 32 * mg + 16 * qt + ln16;
      #pragma unroll
      for (int kt = 0; kt < 4; kt++) {
        f32x4 bv = *(const f32x4_a*)(bias16F + h * 4096 + mg * 2048 + qt * 1024 + kt * 256 + lane * 4);
        int bi = q * 64 + 16 * kt + 4 * lq;
        f32x4 cv;
        if (isbf) {
          u64_a mw = *(const u64_a*)(mk16 + rem * 4096 + bi);
          cv[0] = bv[0] + bf2f((u16)mw) * LOG2E;
          cv[1] = bv[1] + bf2f((u16)(mw >> 16)) * LOG2E;
          cv[2] = bv[2] + bf2f((u16)(mw >> 32)) * LOG2E;
          cv[3] = bv[3] + bf2f((u16)(mw >> 48)) * LOG2E;
        } else {
          f32x4 mv = *(const f32x4_a*)(mkf + rem * 4096 + bi);
          cv = bv + mv * LOG2E;
        }
        ST[kt][qt] = cv;
      }
    }
  }

  bf16x8 kf[4], qf[2];
  #pragma unroll
  for (int kt = 0; kt < 4; kt++)
    kf[kt] = *(const bf16x8_a*)(lds + K_OFF + sw(16 * kt + ln16, h * 32 + q8, 128));
  #pragma unroll
  for (int qt = 0; qt < 2; qt++)
    qf[qt] = *(const bf16x8_a*)(lds + XQ_OFF + sw(32 * mg + 16 * qt + ln16, h * 32 + q8, 128));

  #pragma unroll
  for (int kt = 0; kt < 4; kt++)
    #pragma unroll
    for (int qt = 0; qt < 2; qt++)
      ST[kt][qt] = __builtin_amdgcn_mfma_f32_16x16x32_bf16(kf[kt], qf[qt], ST[kt][qt], 0, 0, 0);

  // softmax over k (rows of S^T), exp2 domain
  #pragma unroll
  for (int qt = 0; qt < 2; qt++) {
    float m = ST[0][qt][0];
    #pragma unroll
    for (int kt = 0; kt < 4; kt++)
      #pragma unroll
      for (int r = 0; r < 4; r++) m = fmaxf(m, ST[kt][qt][r]);
    m = fmaxf(m, __shfl_xor(m, 16));
    m = fmaxf(m, __shfl_xor(m, 32));
    float sum = 0.f;
    #pragma unroll
    for (int kt = 0; kt < 4; kt++)
      #pragma unroll
      for (int r = 0; r < 4; r++) {
        float p = exp2f(ST[kt][qt][r] - m);
        ST[kt][qt][r] = p;
        sum += p;
      }
    sum += __shfl_xor(sum, 16);
    sum += __shfl_xor(sum, 32);
    float inv = 1.0f / sum;
    #pragma unroll
    for (int kt = 0; kt < 4; kt++)
      #pragma unroll
      for (int r = 0; r < 4; r++) ST[kt][qt][r] *= inv;
  }
  __syncthreads();  // B2: all Q/K reads done before P overlays [0,16K)

  // ---- stage 4/5: P -> LDS (intra-wave, no barrier), O = P @ V ----
  #pragma unroll
  for (int qt = 0; qt < 2; qt++)
    #pragma unroll
    for (int kt = 0; kt < 4; kt++) {
      int row = 32 * mg + 16 * qt + ln16;
      int col = h * 64 + 16 * kt + 4 * lq;
      unsigned int w0 = (unsigned int)f2bf(ST[kt][qt][0]) | ((unsigned int)f2bf(ST[kt][qt][1]) << 16);
      unsigned int w1 = (unsigned int)f2bf(ST[kt][qt][2]) | ((unsigned int)f2bf(ST[kt][qt][3]) << 16);
      i32x2 wv = {(int)w0, (int)w1};
      *(i32x2_a*)(lds + P_OFF + sw(row, col, 256)) = wv;
    }
  f32x4 O[2][2];
  O[0][0] = fz; O[0][1] = fz; O[1][0] = fz; O[1][1] = fz;
  #pragma unroll
  for (int ks = 0; ks < 2; ks++) {
    bf16x8 pf[2], vf[2];
    #pragma unroll
    for (int mt = 0; mt < 2; mt++)
      pf[mt] = *(const bf16x8_a*)(lds + P_OFF + sw(32 * mg + 16 * mt + ln16, h * 64 + 32 * ks + q8, 256));
    #pragma unroll
    for (int nt = 0; nt < 2; nt++)
      vf[nt] = *(const bf16x8_a*)(lds + VT_OFF + sw(h * 32 + 16 * nt + ln16, 32 * ks + q8, 64));
    #pragma unroll
    for (int mt = 0; mt < 2; mt++)
      #pragma unroll
      for (int nt = 0; nt < 2; nt++)
        O[mt][nt] = __builtin_amdgcn_mfma_f32_16x16x32_bf16(pf[mt], vf[nt], O[mt][nt], 0, 0, 0);
  }
  __syncthreads();  // B3: all VT reads done before AO overlays it
  #pragma unroll
  for (int mt = 0; mt < 2; mt++)
    #pragma unroll
    for (int nt = 0; nt < 2; nt++)
      #pragma unroll
      for (int r = 0; r < 4; r++) {
        int row = 32 * mg + 16 * mt + 4 * lq + r;
        lds[AO_OFF + sw(row, h * 32 + 16 * nt + ln16, 128)] = f2bf(O[mt][nt][r]);
      }
  __syncthreads();  // B4: AO visible (cross-wave)

  // ---- stage 6: out = AO @ proj_w + proj_b (bias folded into C init) ----
  float pb0 = pbf[32 * sub + ln16];
  float pb1 = pbf[32 * sub + 16 + ln16];
  f32x4 acc3[2][2];
  acc3[0][0] = splat4(pb0); acc3[0][1] = splat4(pb1);
  acc3[1][0] = acc3[0][0];  acc3[1][1] = acc3[0][1];
  #pragma unroll
  for (int ks = 0; ks < 4; ks++) {
    bf16x8 a0 = *(const bf16x8_a*)(lds + AO_OFF + sw(32 * mg + ln16, 32 * ks + q8, 128));
    bf16x8 a1 = *(const bf16x8_a*)(lds + AO_OFF + sw(32 * mg + 16 + ln16, 32 * ks + q8, 128));
    bf16x8 b0 = *(const bf16x8_a*)(pwF + (((sub * 2 + 0) * 4 + ks) << 9) + lane * 8);
    bf16x8 b1 = *(const bf16x8_a*)(pwF + (((sub * 2 + 1) * 4 + ks) << 9) + lane * 8);
    acc3[0][0] = __builtin_amdgcn_mfma_f32_16x16x32_bf16(a0, b0, acc3[0][0], 0, 0, 0);
    acc3[0][1] = __builtin_amdgcn_mfma_f32_16x16x32_bf16(a0, b1, acc3[0][1], 0, 0, 0);
    acc3[1][0] = __builtin_amdgcn_mfma_f32_16x16x32_bf16(a1, b0, acc3[1][0], 0, 0, 0);
    acc3[1][1] = __builtin_amdgcn_mfma_f32_16x16x32_bf16(a1, b1, acc3[1][1], 0, 0, 0);
  }
  if (isbf) {
    u16* ob = (u16*)out;
    #pragma unroll
    for (int mt = 0; mt < 2; mt++)
      #pragma unroll
      for (int r = 0; r < 4; r++) {
        int row = 32 * mg + 16 * mt + 4 * lq + r;
        int o = xbase + (row >> 3) * 16384 + (row & 7) * 128 + 32 * sub;
        ob[o + ln16] = f2bf(acc3[mt][0][r]);
        ob[o + 16 + ln16] = f2bf(acc3[mt][1][r]);
      }
  } else {
    float* of = (float*)out;
    #pragma unroll
    for (int mt = 0; mt < 2; mt++)
      #pragma unroll
      for (int r = 0; r < 4; r++) {
        int row = 32 * mg + 16 * mt + 4 * lq + r;
        int o = xbase + (row >> 3) * 16384 + (row & 7) * 128 + 32 * sub;
        of[o + ln16] = acc3[mt][0][r];
        of[o + 16 + ln16] = acc3[mt][1][r];
      }
  }
}

extern "C" void kernel_launch(void* const* d_in, const int* in_sizes, int n_in,
                              void* d_out, int out_size, void* d_ws, size_t ws_size,
                              hipStream_t stream) {
  const void* x      = d_in[0];
  const void* mask   = d_in[1];
  const void* qkv_w  = d_in[2];
  const void* q_bias = d_in[3];
  const void* v_bias = d_in[4];
  const void* ls     = d_in[5];
  const void* cpb_w1 = d_in[6];
  const void* cpb_b1 = d_in[7];
  const void* cpb_w2 = d_in[8];
  const void* proj_w = d_in[9];
  const void* proj_b = d_in[10];
  const int B = in_sizes[0] / (128 * 128 * 128);

  char* ws = (char*)d_ws;
  swin_detect<<<1, 64, 0, stream>>>((const unsigned int*)x,
                                    (unsigned int*)(ws + FLAG_OFF));
  swin_setup<<<258, 256, 0, stream>>>(qkv_w, q_bias, v_bias, ls, cpb_w1, cpb_b1,
                                      cpb_w2, proj_w, proj_b, ws);
  if (ws_size >= MASKF_NEED) {
    swin_setup_mask<<<256, 256, 0, stream>>>(mask, ws);
    swin_main<1><<<B * 256, 512, 0, stream>>>(x, mask, ws, d_out);
  } else {
    swin_main<0><<<B * 256, 512, 0, stream>>>(x, mask, ws, d_out);
  }
}